// Round 13
// baseline (266.385 us; speedup 1.0000x reference)
//
#include <hip/hip_runtime.h>
#include <stdint.h>

#define D_MODEL 1024
#define NHEAD   16
#define DHEAD   64
#define BATCH   4
#define SEQ     2048
#define MTOT    (BATCH*SEQ)   // 8192

typedef __attribute__((ext_vector_type(4)))  float f32x4;
typedef __attribute__((ext_vector_type(8)))  short bf16x8;

typedef __attribute__((address_space(3))) uint32_t lds_u32;
typedef const __attribute__((address_space(1))) uint32_t glb_u32;

__device__ static inline void gload_lds16(const void* g, void* l) {
    __builtin_amdgcn_global_load_lds((glb_u32*)g, (lds_u32*)l, 16, 0, 0);
}

__device__ static inline ushort f2bf(float f) {
    uint32_t u = __builtin_bit_cast(uint32_t, f);
    u += 0x7fffu + ((u >> 16) & 1u);   // RNE (inputs are finite)
    return (ushort)(u >> 16);
}

__device__ static inline float exp2_fast(float x) {
    float r; asm("v_exp_f32 %0, %1" : "=v"(r) : "v"(x)); return r;
}
__device__ static inline uint32_t cvt_pk_bf16(float a, float b) {
    uint32_t r;  // low half = bf16(a), high half = bf16(b)
    asm("v_cvt_pk_bf16_f32 %0, %1, %2" : "=v"(r) : "v"(a), "v"(b));
    return r;
}

// ---------------------------------------------------------------- convert
__global__ __launch_bounds__(256) void convert_kernel(
    const float4* __restrict__ x,
    const float4* __restrict__ wq, const float4* __restrict__ wk,
    const float4* __restrict__ wv, const float4* __restrict__ wo,
    ushort4* __restrict__ xb, ushort4* __restrict__ wb)
{
    const int NX4 = (MTOT * D_MODEL) / 4;
    const int NW4 = (D_MODEL * D_MODEL) / 4;
    const int TOT = NX4 + 4 * NW4;
    for (int i = blockIdx.x * blockDim.x + threadIdx.x; i < TOT;
         i += gridDim.x * blockDim.x) {
        float4 v; ushort4* dst;
        if (i < NX4) { v = x[i]; dst = &xb[i]; }
        else {
            int j = i - NX4;
            int w = j >> 18;
            int r = j & (NW4 - 1);
            const float4* s = (w == 0) ? wq : (w == 1) ? wk : (w == 2) ? wv : wo;
            v = s[r]; dst = &wb[(size_t)w * NW4 + r];
        }
        ushort4 o;
        o.x = f2bf(v.x); o.y = f2bf(v.y); o.z = f2bf(v.z); o.w = f2bf(v.w);
        *dst = o;
    }
}

// =================================================================
// 256x256 GEMM, BK=64, 512 threads = 8 waves (2m x 4n), wave tile
// 128x64 -> 42.7 FLOP per LDS byte read. 2-phase double-buffered
// pipeline (proven R10). 8-granule XOR swizzle, pre-swizzled global
// source + linear gload dest (rule #21; 0 conflicts measured).
// =================================================================

#define GEMM256_BODY(APTR, BPTR)                                            \
    __shared__ __align__(16) ushort S[2 * 32768]; /* [buf][A 16K|B 16K] */  \
    const int tid = threadIdx.x;                                            \
    const int w = tid >> 6, l = tid & 63;                                   \
    const int lo = l & 15, hi = l >> 4;          /* hi 0..3 */              \
    const int wm = w >> 2, wn = w & 3;           /* 2m x 4n */              \
    const int sr = l >> 3, sg = l & 7;                                      \
    f32x4 acc[8][4] = {};                                                   \
    auto stage = [&](int buf, int kt) {                                     \
        ushort* SP = &S[buf * 32768];                                       \
        _Pragma("unroll")                                                   \
        for (int j = 0; j < 4; ++j) {                                       \
            const int row = w * 32 + j * 8 + sr;                            \
            const int g = sg ^ sr;              /* row&7 == sr */           \
            gload_lds16((APTR) + (size_t)(m0 + row) * 1024 + kt * 64 + g * 8,\
                        SP + (w * 32 + j * 8) * 64);                        \
            gload_lds16((BPTR) + (size_t)(n0 + row) * 1024 + kt * 64 + g * 8,\
                        SP + 16384 + (w * 32 + j * 8) * 64);                \
        }                                                                   \
    };                                                                      \
    stage(0, 0);                                                            \
    asm volatile("s_waitcnt vmcnt(0)" ::: "memory");                        \
    __builtin_amdgcn_s_barrier();                                           \
    __builtin_amdgcn_sched_barrier(0);                                      \
    int cur = 0;                                                            \
    for (int kt = 0; kt < 16; ++kt) {                                       \
        if (kt + 1 < 16) stage(cur ^ 1, kt + 1);                            \
        const char* SA = (const char*)&S[cur * 32768];                      \
        const char* SB = SA + 32768;                                        \
        _Pragma("unroll")                                                   \
        for (int ks = 0; ks < 2; ++ks) {                                    \
            bf16x8 af[8], bfr[4];                                           \
            _Pragma("unroll")                                               \
            for (int mi = 0; mi < 8; ++mi) {                                \
                const int r = wm * 128 + mi * 16 + lo;                      \
                af[mi] = *(const bf16x8*)(SA + r * 128 +                    \
                          (((ks * 4 + hi) ^ (r & 7)) << 4));                \
            }                                                               \
            _Pragma("unroll")                                               \
            for (int ni = 0; ni < 4; ++ni) {                                \
                const int c = wn * 64 + ni * 16 + lo;                       \
                bfr[ni] = *(const bf16x8*)(SB + c * 128 +                   \
                          (((ks * 4 + hi) ^ (c & 7)) << 4));                \
            }                                                               \
            asm volatile("s_waitcnt lgkmcnt(0)" ::: "memory");              \
            __builtin_amdgcn_sched_barrier(0);                              \
            __builtin_amdgcn_s_setprio(1);                                  \
            _Pragma("unroll")                                               \
            for (int mi = 0; mi < 8; ++mi)                                  \
                _Pragma("unroll")                                           \
                for (int ni = 0; ni < 4; ++ni)                              \
                    acc[mi][ni] = __builtin_amdgcn_mfma_f32_16x16x32_bf16(  \
                        af[mi], bfr[ni], acc[mi][ni], 0, 0, 0);             \
            __builtin_amdgcn_s_setprio(0);                                  \
        }                                                                   \
        if (kt + 1 < 16) {                                                  \
            asm volatile("s_waitcnt vmcnt(0)" ::: "memory");                \
            __builtin_amdgcn_s_barrier();                                   \
            __builtin_amdgcn_sched_barrier(0);                              \
        }                                                                   \
        cur ^= 1;                                                           \
    }

// ---------------------------------------------------------------- fused QKV GEMM
__global__ __launch_bounds__(512) void gemm_qkv(
    const ushort* __restrict__ A,    // [8192,1024] bf16
    const ushort* __restrict__ W3,   // [3072,1024] bf16
    const float* __restrict__ bq, const float* __restrict__ bk,
    const float* __restrict__ bv,
    ushort* __restrict__ Qb, ushort* __restrict__ Kb, ushort* __restrict__ Vtb,
    float qscale)
{
    const int id = blockIdx.x;              // 0..383
    const int xcd = id & 7, q = id >> 3;    // q 0..47
    const int mb = xcd * 4 + (q & 3);       // 0..31 (2MB A-chunk per XCD)
    const int nb = q >> 2;                  // 0..11
    const int m0 = mb * 256, n0 = nb * 256;

    GEMM256_BODY(A, W3)

    const int region = nb >> 2;             // 0:Q 1:K 2:V (block-uniform)
    const float scale = (region == 0) ? qscale : 1.0f;
    const float* bias = (region == 0) ? bq : (region == 1) ? bk : bv;
    ushort* outQK = (region == 0) ? Qb : Kb;

#pragma unroll
    for (int mi = 0; mi < 8; ++mi) {
#pragma unroll
        for (int ni = 0; ni < 4; ++ni) {
            const int gj  = n0 + wn * 64 + ni * 16 + lo;   // 0..3071
            const int lcl = gj & 1023;
            const int h = lcl >> 6, dh = lcl & 63;
            const float bj = bias[lcl];
            const int gi0 = m0 + wm * 128 + mi * 16 + hi * 4;
            const int b = gi0 >> 11, s0 = gi0 & (SEQ - 1);
            if (region < 2) {
#pragma unroll
                for (int r = 0; r < 4; ++r)
                    outQK[(((size_t)(b * NHEAD + h)) * SEQ + s0 + r) * DHEAD + dh] =
                        f2bf((acc[mi][ni][r] + bj) * scale);
            } else {
                ushort4 o4;
                o4.x = f2bf(acc[mi][ni][0] + bj);
                o4.y = f2bf(acc[mi][ni][1] + bj);
                o4.z = f2bf(acc[mi][ni][2] + bj);
                o4.w = f2bf(acc[mi][ni][3] + bj);
                *(ushort4*)&Vtb[(((size_t)(b * NHEAD + h)) * DHEAD + dh) * SEQ + s0] = o4;
            }
        }
    }
}

// ---------------------------------------------------------------- output GEMM
__global__ __launch_bounds__(512) void gemm_out(
    const ushort* __restrict__ A,
    const ushort* __restrict__ W,
    const float*  __restrict__ bias,
    float* __restrict__ out)
{
    const int id = blockIdx.x;              // 0..127
    const int xcd = id & 7, q = id >> 3;    // q 0..15
    const int mb = xcd * 4 + (q & 3);       // 0..31
    const int nb = q >> 2;                  // 0..3
    const int m0 = mb * 256, n0 = nb * 256;

    GEMM256_BODY(A, W)

#pragma unroll
    for (int mi = 0; mi < 8; ++mi)
#pragma unroll
        for (int ni = 0; ni < 4; ++ni) {
            const int gj = n0 + wn * 64 + ni * 16 + lo;
            const float bj = bias[gj];
            const int gi0 = m0 + wm * 128 + mi * 16 + hi * 4;
#pragma unroll
            for (int r = 0; r < 4; ++r)
                out[(size_t)(gi0 + r) * D_MODEL + gj] = acc[mi][ni][r] + bj;
        }
}

// ---------------------------------------------------------------- attention
// Swapped-QK^T flash attention, exp2 domain (Q pre-scaled by log2e/8).
// R10 body, but ONE Q-tile per block -> 1024 blocks = 4 blocks/CU
// (grid was the occupancy limiter at 512). Per-CU balance is exact:
// co-resident blocks (fid +256k) get qts {j, j+4, 15-j, 11-j} ->
// sum(ntiles) = 68 per CU, same as the old paired scheme. Same-CU
// blocks share bh -> K/V streams L1/L2-coherent.
// Depth-2 K/V prefetch with STATIC register buffers (rule #20).
// LDS [64][64] bf16, 16B-granule XOR swizzle. 32KB/block.
__global__ __launch_bounds__(256, 4) void attn_kernel(
    const ushort* __restrict__ Q, const ushort* __restrict__ K,
    const ushort* __restrict__ Vt, ushort* __restrict__ ctx)
{
    __shared__ __align__(16) ushort Ks[64 * 64];
    __shared__ __align__(16) ushort Vs[64 * 64];
    __shared__ __align__(16) ushort Pq[4 * 32 * 64];

    const int tid = threadIdx.x;
    const int w = tid >> 6, l = tid & 63, lo = l & 15, hi = l >> 4;
    const int sw = lo & 7;

    const int fid = blockIdx.x;            // 0..1023
    const int xcd = fid & 7;
    const int g = xcd * 8 + ((fid >> 3) & 7);   // bh; g>>3 == xcd
    const int b = g >> 4, h = g & 15;
    const int j = (fid >> 6) & 7;
    const int half = fid >> 9;
    const int qt = half ? (15 - j) : j;    // each (bh,qt) exactly once
    const size_t base = (size_t)(b * NHEAD + h) * SEQ * DHEAD;

    const int krow = tid >> 3;             // 0..31
    const int kcol = (tid & 7) * 8;
    char* PqW = (char*)&Pq[w * 2048];

    const int q0 = qt << 7;
    const int qw0 = q0 + w * 32;

    bf16x8 qf[2][2];
#pragma unroll
    for (int mi = 0; mi < 2; ++mi)
#pragma unroll
        for (int ks = 0; ks < 2; ++ks)
            qf[mi][ks] = *(const bf16x8*)&Q[base +
                (size_t)(qw0 + mi * 16 + lo) * DHEAD + ks * 32 + hi * 8];

    f32x4 o[2][4] = {};
    float mrow[2] = {-1e30f, -1e30f}, lrow[2] = {0.f, 0.f};

    const int ntiles = (q0 + 128) >> 6;   // = 2*(qt+1), always even

    bf16x8 kregA[2], vregA[2], kregB[2], vregB[2];
#pragma unroll
    for (int c = 0; c < 2; ++c) {          // prologue: tiles 0 and 1
        kregA[c] = *(const bf16x8*)&K[base + (size_t)(c * 32 + krow) * DHEAD + kcol];
        vregA[c] = *(const bf16x8*)&Vt[base + (size_t)(c * 32 + krow) * SEQ + kcol];
        kregB[c] = *(const bf16x8*)&K[base + (size_t)(64 + c * 32 + krow) * DHEAD + kcol];
        vregB[c] = *(const bf16x8*)&Vt[base + (size_t)(c * 32 + krow) * SEQ + 64 + kcol];
    }

    auto tile_body = [&](int t, bf16x8 (&KR)[2], bf16x8 (&VR)[2]) {
        const int kv0 = t << 6;
        __syncthreads();                 // prev tile's LDS reads done
#pragma unroll
        for (int c = 0; c < 2; ++c) {    // stage K/V (swizzled)
            const int row = c * 32 + krow;
            const int g16 = (tid & 7) ^ (row & 7);
            *(bf16x8*)((char*)Ks + row * 128 + (g16 << 4)) = KR[c];
            *(bf16x8*)((char*)Vs + row * 128 + (g16 << 4)) = VR[c];
        }
        __syncthreads();
        if (t + 2 < ntiles) {            // depth-2 prefetch (T14)
            const int nv0 = kv0 + 128;
#pragma unroll
            for (int c = 0; c < 2; ++c) {
                KR[c] = *(const bf16x8*)&K[base + (size_t)(nv0 + c * 32 + krow) * DHEAD + kcol];
                VR[c] = *(const bf16x8*)&Vt[base + (size_t)(c * 32 + krow) * SEQ + nv0 + kcol];
            }
        }
        if (kv0 > qw0 + 31) return;      // wave fully masked (barriers balanced)

        // ---- S^T = K Q^T  (rows=kv, cols=q=lo), log2-scaled
        f32x4 s[2][4] = {};
        __builtin_amdgcn_s_setprio(1);
#pragma unroll
        for (int ks = 0; ks < 2; ++ks) {
            bf16x8 kf[4];
#pragma unroll
            for (int nj = 0; nj < 4; ++nj)
                kf[nj] = *(const bf16x8*)((char*)Ks + (nj * 16 + lo) * 128 +
                                          ((((ks << 2) + hi) ^ sw) << 4));
#pragma unroll
            for (int mi = 0; mi < 2; ++mi)
#pragma unroll
                for (int nj = 0; nj < 4; ++nj)
                    s[mi][nj] = __builtin_amdgcn_mfma_f32_16x16x32_bf16(
                        kf[nj], qf[mi][ks], s[mi][nj], 0, 0, 0);
        }
        __builtin_amdgcn_s_setprio(0);

        // ---- causal mask
        if (kv0 + 63 > qw0) {
#pragma unroll
            for (int mi = 0; mi < 2; ++mi) {
                const int gq = qw0 + mi * 16 + lo;
#pragma unroll
                for (int nj = 0; nj < 4; ++nj)
#pragma unroll
                    for (int r = 0; r < 4; ++r) {
                        const int gk = kv0 + nj * 16 + hi * 4 + r;
                        if (gk > gq) s[mi][nj][r] = -1e30f;
                    }
            }
        }

        // ---- online softmax (q=lo lane-local), defer-max THR=8 (log2)
        float tl[2], corr[2];
#pragma unroll
        for (int mi = 0; mi < 2; ++mi) {
            float m = s[mi][0][0];
#pragma unroll
            for (int nj = 0; nj < 4; ++nj)
#pragma unroll
                for (int r = 0; r < 4; ++r) m = fmaxf(m, s[mi][nj][r]);
            tl[mi] = m;
        }
        const bool grow = (tl[0] > mrow[0] + 8.f) | (tl[1] > mrow[1] + 8.f);
        if (__any(grow)) {
#pragma unroll
            for (int mi = 0; mi < 2; ++mi) {
                float m2 = fmaxf(tl[mi], __shfl_xor(tl[mi], 16));
                m2 = fmaxf(m2, __shfl_xor(m2, 32));
                const float mn = fmaxf(mrow[mi], m2);
                corr[mi] = exp2_fast(mrow[mi] - mn);
                mrow[mi] = mn;
            }
#pragma unroll
            for (int mi = 0; mi < 2; ++mi)
#pragma unroll
                for (int r = 0; r < 4; ++r) {
                    const float cb = __shfl(corr[mi], hi * 4 + r);
#pragma unroll
                    for (int ni = 0; ni < 4; ++ni) o[mi][ni][r] *= cb;
                }
        } else { corr[0] = 1.f; corr[1] = 1.f; }

#pragma unroll
        for (int mi = 0; mi < 2; ++mi) {
            float ls = 0.f;
#pragma unroll
            for (int nj = 0; nj < 4; ++nj) {
#pragma unroll
                for (int r = 0; r < 4; ++r) {
                    const float p = exp2_fast(s[mi][nj][r] - mrow[mi]);
                    s[mi][nj][r] = p;
                    ls += p;
                }
                uint2 pp;
                pp.x = cvt_pk_bf16(s[mi][nj][0], s[mi][nj][1]);
                pp.y = cvt_pk_bf16(s[mi][nj][2], s[mi][nj][3]);
                const int gP = ((nj << 1) + (hi >> 1)) ^ sw;
                *(uint2*)(PqW + (mi * 16 + lo) * 128 + (gP << 4) + ((hi & 1) << 3)) = pp;
            }
            ls += __shfl_xor(ls, 16);
            ls += __shfl_xor(ls, 32);
            lrow[mi] = lrow[mi] * corr[mi] + ls;
        }

        // ---- O += P V
        __builtin_amdgcn_s_setprio(1);
#pragma unroll
        for (int ks2 = 0; ks2 < 2; ++ks2) {
            bf16x8 pf[2], vf[4];
#pragma unroll
            for (int mi = 0; mi < 2; ++mi)
                pf[mi] = *(const bf16x8*)(PqW + (mi * 16 + lo) * 128 +
                                          ((((ks2 << 2) + hi) ^ sw) << 4));
#pragma unroll
            for (int ni = 0; ni < 4; ++ni)
                vf[ni] = *(const bf16x8*)((char*)Vs + (ni * 16 + lo) * 128 +
                                          ((((ks2 << 2) + hi) ^ sw) << 4));
#pragma unroll
            for (int mi = 0; mi < 2; ++mi)
#pragma unroll
                for (int ni = 0; ni < 4; ++ni)
                    o[mi][ni] = __builtin_amdgcn_mfma_f32_16x16x32_bf16(
                        pf[mi], vf[ni], o[mi][ni], 0, 0, 0);
        }
        __builtin_amdgcn_s_setprio(0);
    };

    for (int tt = 0; tt < ntiles; tt += 2) {
        tile_body(tt,     kregA, vregA);   // even tile: buffer A
        tile_body(tt + 1, kregB, vregB);   // odd tile:  buffer B
    }

    // ---- epilogue
#pragma unroll
    for (int mi = 0; mi < 2; ++mi) {
        const float rv = 1.0f / lrow[mi];
#pragma unroll
        for (int r = 0; r < 4; ++r) {
            const float rb = __shfl(rv, hi * 4 + r);
            const int gq = qw0 + mi * 16 + hi * 4 + r;
#pragma unroll
            for (int ni = 0; ni < 4; ++ni)
                ctx[((size_t)(b * SEQ + gq)) * D_MODEL + h * DHEAD + ni * 16 + lo] =
                    f2bf(o[mi][ni][r] * rb);
        }
    }
}

// ---------------------------------------------------------------- launch
extern "C" void kernel_launch(void* const* d_in, const int* in_sizes, int n_in,
                              void* d_out, int out_size, void* d_ws, size_t ws_size,
                              hipStream_t stream) {
    const float* x  = (const float*)d_in[0];
    const float* Wq = (const float*)d_in[1];
    const float* bq = (const float*)d_in[2];
    const float* Wk = (const float*)d_in[3];
    const float* bk = (const float*)d_in[4];
    const float* Wv = (const float*)d_in[5];
    const float* bv = (const float*)d_in[6];
    const float* Wo = (const float*)d_in[7];
    const float* bo = (const float*)d_in[8];

    char* ws = (char*)d_ws;
    ushort* xb  = (ushort*)(ws);
    ushort* wb  = (ushort*)(ws + (16u << 20));
    ushort* Qb  = (ushort*)(ws + (24u << 20));
    ushort* Kb  = (ushort*)(ws + (40u << 20));
    ushort* Vtb = (ushort*)(ws + (56u << 20));
    ushort* ctx = (ushort*)(ws + (72u << 20));

    convert_kernel<<<2048, 256, 0, stream>>>(
        (const float4*)x, (const float4*)Wq, (const float4*)Wk,
        (const float4*)Wv, (const float4*)Wo, (ushort4*)xb, (ushort4*)wb);

    const int NW = D_MODEL * D_MODEL;
    const float qscale = 0.125f * 1.44269504f;   // fold log2e: softmax in exp2 domain

    gemm_qkv<<<384, 512, 0, stream>>>(xb, wb, bq, bk, bv, Qb, Kb, Vtb, qscale);

    attn_kernel<<<1024, 256, 0, stream>>>(Qb, Kb, Vtb, ctx);

    gemm_out<<<128, 512, 0, stream>>>(ctx, wb + 3 * NW, bo, (float*)d_out);
}

// Round 14
// 171.000 us; speedup vs baseline: 1.5578x; 1.5578x over previous
//
#include <hip/hip_runtime.h>
#include <stdint.h>

#define D_MODEL 1024
#define NHEAD   16
#define DHEAD   64
#define BATCH   4
#define SEQ     2048
#define MTOT    (BATCH*SEQ)   // 8192

typedef __attribute__((ext_vector_type(4)))  float f32x4;
typedef __attribute__((ext_vector_type(8)))  short bf16x8;

typedef __attribute__((address_space(3))) uint32_t lds_u32;
typedef const __attribute__((address_space(1))) uint32_t glb_u32;

__device__ static inline void gload_lds16(const void* g, void* l) {
    __builtin_amdgcn_global_load_lds((glb_u32*)g, (lds_u32*)l, 16, 0, 0);
}

__device__ static inline ushort f2bf(float f) {
    uint32_t u = __builtin_bit_cast(uint32_t, f);
    u += 0x7fffu + ((u >> 16) & 1u);   // RNE (inputs are finite)
    return (ushort)(u >> 16);
}

__device__ static inline float exp2_fast(float x) {
    float r; asm("v_exp_f32 %0, %1" : "=v"(r) : "v"(x)); return r;
}
__device__ static inline uint32_t cvt_pk_bf16(float a, float b) {
    uint32_t r;  // low half = bf16(a), high half = bf16(b)
    asm("v_cvt_pk_bf16_f32 %0, %1, %2" : "=v"(r) : "v"(a), "v"(b));
    return r;
}

// ---------------------------------------------------------------- convert
__global__ __launch_bounds__(256) void convert_kernel(
    const float4* __restrict__ x,
    const float4* __restrict__ wq, const float4* __restrict__ wk,
    const float4* __restrict__ wv, const float4* __restrict__ wo,
    ushort4* __restrict__ xb, ushort4* __restrict__ wb)
{
    const int NX4 = (MTOT * D_MODEL) / 4;
    const int NW4 = (D_MODEL * D_MODEL) / 4;
    const int TOT = NX4 + 4 * NW4;
    for (int i = blockIdx.x * blockDim.x + threadIdx.x; i < TOT;
         i += gridDim.x * blockDim.x) {
        float4 v; ushort4* dst;
        if (i < NX4) { v = x[i]; dst = &xb[i]; }
        else {
            int j = i - NX4;
            int w = j >> 18;
            int r = j & (NW4 - 1);
            const float4* s = (w == 0) ? wq : (w == 1) ? wk : (w == 2) ? wv : wo;
            v = s[r]; dst = &wb[(size_t)w * NW4 + r];
        }
        ushort4 o;
        o.x = f2bf(v.x); o.y = f2bf(v.y); o.z = f2bf(v.z); o.w = f2bf(v.w);
        *dst = o;
    }
}

// =================================================================
// 256x256 GEMM, BK=64, 512 threads = 8 waves (2m x 4n), wave tile
// 128x64 -> 42.7 FLOP per LDS byte read. 2-phase double-buffered
// pipeline (proven R10). 8-granule XOR swizzle, pre-swizzled global
// source + linear gload dest (rule #21; 0 conflicts measured).
// =================================================================

#define GEMM256_BODY(APTR, BPTR)                                            \
    __shared__ __align__(16) ushort S[2 * 32768]; /* [buf][A 16K|B 16K] */  \
    const int tid = threadIdx.x;                                            \
    const int w = tid >> 6, l = tid & 63;                                   \
    const int lo = l & 15, hi = l >> 4;          /* hi 0..3 */              \
    const int wm = w >> 2, wn = w & 3;           /* 2m x 4n */              \
    const int sr = l >> 3, sg = l & 7;                                      \
    f32x4 acc[8][4] = {};                                                   \
    auto stage = [&](int buf, int kt) {                                     \
        ushort* SP = &S[buf * 32768];                                       \
        _Pragma("unroll")                                                   \
        for (int j = 0; j < 4; ++j) {                                       \
            const int row = w * 32 + j * 8 + sr;                            \
            const int g = sg ^ sr;              /* row&7 == sr */           \
            gload_lds16((APTR) + (size_t)(m0 + row) * 1024 + kt * 64 + g * 8,\
                        SP + (w * 32 + j * 8) * 64);                        \
            gload_lds16((BPTR) + (size_t)(n0 + row) * 1024 + kt * 64 + g * 8,\
                        SP + 16384 + (w * 32 + j * 8) * 64);                \
        }                                                                   \
    };                                                                      \
    stage(0, 0);                                                            \
    asm volatile("s_waitcnt vmcnt(0)" ::: "memory");                        \
    __builtin_amdgcn_s_barrier();                                           \
    __builtin_amdgcn_sched_barrier(0);                                      \
    int cur = 0;                                                            \
    for (int kt = 0; kt < 16; ++kt) {                                       \
        if (kt + 1 < 16) stage(cur ^ 1, kt + 1);                            \
        const char* SA = (const char*)&S[cur * 32768];                      \
        const char* SB = SA + 32768;                                        \
        _Pragma("unroll")                                                   \
        for (int ks = 0; ks < 2; ++ks) {                                    \
            bf16x8 af[8], bfr[4];                                           \
            _Pragma("unroll")                                               \
            for (int mi = 0; mi < 8; ++mi) {                                \
                const int r = wm * 128 + mi * 16 + lo;                      \
                af[mi] = *(const bf16x8*)(SA + r * 128 +                    \
                          (((ks * 4 + hi) ^ (r & 7)) << 4));                \
            }                                                               \
            _Pragma("unroll")                                               \
            for (int ni = 0; ni < 4; ++ni) {                                \
                const int c = wn * 64 + ni * 16 + lo;                       \
                bfr[ni] = *(const bf16x8*)(SB + c * 128 +                   \
                          (((ks * 4 + hi) ^ (c & 7)) << 4));                \
            }                                                               \
            asm volatile("s_waitcnt lgkmcnt(0)" ::: "memory");              \
            __builtin_amdgcn_sched_barrier(0);                              \
            __builtin_amdgcn_s_setprio(1);                                  \
            _Pragma("unroll")                                               \
            for (int mi = 0; mi < 8; ++mi)                                  \
                _Pragma("unroll")                                           \
                for (int ni = 0; ni < 4; ++ni)                              \
                    acc[mi][ni] = __builtin_amdgcn_mfma_f32_16x16x32_bf16(  \
                        af[mi], bfr[ni], acc[mi][ni], 0, 0, 0);             \
            __builtin_amdgcn_s_setprio(0);                                  \
        }                                                                   \
        if (kt + 1 < 16) {                                                  \
            asm volatile("s_waitcnt vmcnt(0)" ::: "memory");                \
            __builtin_amdgcn_s_barrier();                                   \
            __builtin_amdgcn_sched_barrier(0);                              \
        }                                                                   \
        cur ^= 1;                                                           \
    }

// ---------------------------------------------------------------- fused QKV GEMM
__global__ __launch_bounds__(512) void gemm_qkv(
    const ushort* __restrict__ A,    // [8192,1024] bf16
    const ushort* __restrict__ W3,   // [3072,1024] bf16
    const float* __restrict__ bq, const float* __restrict__ bk,
    const float* __restrict__ bv,
    ushort* __restrict__ Qb, ushort* __restrict__ Kb, ushort* __restrict__ Vtb,
    float qscale)
{
    const int id = blockIdx.x;              // 0..383
    const int xcd = id & 7, q = id >> 3;    // q 0..47
    const int mb = xcd * 4 + (q & 3);       // 0..31 (2MB A-chunk per XCD)
    const int nb = q >> 2;                  // 0..11
    const int m0 = mb * 256, n0 = nb * 256;

    GEMM256_BODY(A, W3)

    const int region = nb >> 2;             // 0:Q 1:K 2:V (block-uniform)
    const float scale = (region == 0) ? qscale : 1.0f;
    const float* bias = (region == 0) ? bq : (region == 1) ? bk : bv;
    ushort* outQK = (region == 0) ? Qb : Kb;

#pragma unroll
    for (int mi = 0; mi < 8; ++mi) {
#pragma unroll
        for (int ni = 0; ni < 4; ++ni) {
            const int gj  = n0 + wn * 64 + ni * 16 + lo;   // 0..3071
            const int lcl = gj & 1023;
            const int h = lcl >> 6, dh = lcl & 63;
            const float bj = bias[lcl];
            const int gi0 = m0 + wm * 128 + mi * 16 + hi * 4;
            const int b = gi0 >> 11, s0 = gi0 & (SEQ - 1);
            if (region < 2) {
#pragma unroll
                for (int r = 0; r < 4; ++r)
                    outQK[(((size_t)(b * NHEAD + h)) * SEQ + s0 + r) * DHEAD + dh] =
                        f2bf((acc[mi][ni][r] + bj) * scale);
            } else {
                ushort4 o4;
                o4.x = f2bf(acc[mi][ni][0] + bj);
                o4.y = f2bf(acc[mi][ni][1] + bj);
                o4.z = f2bf(acc[mi][ni][2] + bj);
                o4.w = f2bf(acc[mi][ni][3] + bj);
                *(ushort4*)&Vtb[(((size_t)(b * NHEAD + h)) * DHEAD + dh) * SEQ + s0] = o4;
            }
        }
    }
}

// ---------------------------------------------------------------- output GEMM
__global__ __launch_bounds__(512) void gemm_out(
    const ushort* __restrict__ A,
    const ushort* __restrict__ W,
    const float*  __restrict__ bias,
    float* __restrict__ out)
{
    const int id = blockIdx.x;              // 0..127
    const int xcd = id & 7, q = id >> 3;    // q 0..15
    const int mb = xcd * 4 + (q & 3);       // 0..31
    const int nb = q >> 2;                  // 0..3
    const int m0 = mb * 256, n0 = nb * 256;

    GEMM256_BODY(A, W)

#pragma unroll
    for (int mi = 0; mi < 8; ++mi)
#pragma unroll
        for (int ni = 0; ni < 4; ++ni) {
            const int gj = n0 + wn * 64 + ni * 16 + lo;
            const float bj = bias[gj];
            const int gi0 = m0 + wm * 128 + mi * 16 + hi * 4;
#pragma unroll
            for (int r = 0; r < 4; ++r)
                out[(size_t)(gi0 + r) * D_MODEL + gj] = acc[mi][ni][r] + bj;
        }
}

// ---------------------------------------------------------------- attention
// Swapped-QK^T flash attention, exp2 domain (Q pre-scaled by log2e/8).
// ONE Q-tile per block -> 1024 blocks. PLAIN launch_bounds(256):
// R13's (256,4) forced VGPR 64 -> scratch spill (FETCH 152MB). At the
// natural VGPR=128 the HW allows 16 waves/CU = 4 blocks/CU, which is
// the occupancy target (LDS 4x32KB=128KB OK). Per-CU qt balance:
// {j, j+4, 15-j, 11-j} -> 68 tiles. Depth-2 static prefetch (rule #20).
// LDS [64][64] bf16, 16B-granule XOR swizzle.
__global__ __launch_bounds__(256) void attn_kernel(
    const ushort* __restrict__ Q, const ushort* __restrict__ K,
    const ushort* __restrict__ Vt, ushort* __restrict__ ctx)
{
    __shared__ __align__(16) ushort Ks[64 * 64];
    __shared__ __align__(16) ushort Vs[64 * 64];
    __shared__ __align__(16) ushort Pq[4 * 32 * 64];

    const int tid = threadIdx.x;
    const int w = tid >> 6, l = tid & 63, lo = l & 15, hi = l >> 4;
    const int sw = lo & 7;

    const int fid = blockIdx.x;            // 0..1023
    const int xcd = fid & 7;
    const int g = xcd * 8 + ((fid >> 3) & 7);   // bh; g>>3 == xcd
    const int b = g >> 4, h = g & 15;
    const int j = (fid >> 6) & 7;
    const int half = fid >> 9;
    const int qt = half ? (15 - j) : j;    // each (bh,qt) exactly once
    const size_t base = (size_t)(b * NHEAD + h) * SEQ * DHEAD;

    const int krow = tid >> 3;             // 0..31
    const int kcol = (tid & 7) * 8;
    char* PqW = (char*)&Pq[w * 2048];

    const int q0 = qt << 7;
    const int qw0 = q0 + w * 32;

    bf16x8 qf[2][2];
#pragma unroll
    for (int mi = 0; mi < 2; ++mi)
#pragma unroll
        for (int ks = 0; ks < 2; ++ks)
            qf[mi][ks] = *(const bf16x8*)&Q[base +
                (size_t)(qw0 + mi * 16 + lo) * DHEAD + ks * 32 + hi * 8];

    f32x4 o[2][4] = {};
    float mrow[2] = {-1e30f, -1e30f}, lrow[2] = {0.f, 0.f};

    const int ntiles = (q0 + 128) >> 6;   // = 2*(qt+1), always even

    bf16x8 kregA[2], vregA[2], kregB[2], vregB[2];
#pragma unroll
    for (int c = 0; c < 2; ++c) {          // prologue: tiles 0 and 1
        kregA[c] = *(const bf16x8*)&K[base + (size_t)(c * 32 + krow) * DHEAD + kcol];
        vregA[c] = *(const bf16x8*)&Vt[base + (size_t)(c * 32 + krow) * SEQ + kcol];
        kregB[c] = *(const bf16x8*)&K[base + (size_t)(64 + c * 32 + krow) * DHEAD + kcol];
        vregB[c] = *(const bf16x8*)&Vt[base + (size_t)(c * 32 + krow) * SEQ + 64 + kcol];
    }

    auto tile_body = [&](int t, bf16x8 (&KR)[2], bf16x8 (&VR)[2]) {
        const int kv0 = t << 6;
        __syncthreads();                 // prev tile's LDS reads done
#pragma unroll
        for (int c = 0; c < 2; ++c) {    // stage K/V (swizzled)
            const int row = c * 32 + krow;
            const int g16 = (tid & 7) ^ (row & 7);
            *(bf16x8*)((char*)Ks + row * 128 + (g16 << 4)) = KR[c];
            *(bf16x8*)((char*)Vs + row * 128 + (g16 << 4)) = VR[c];
        }
        __syncthreads();
        if (t + 2 < ntiles) {            // depth-2 prefetch (T14)
            const int nv0 = kv0 + 128;
#pragma unroll
            for (int c = 0; c < 2; ++c) {
                KR[c] = *(const bf16x8*)&K[base + (size_t)(nv0 + c * 32 + krow) * DHEAD + kcol];
                VR[c] = *(const bf16x8*)&Vt[base + (size_t)(c * 32 + krow) * SEQ + nv0 + kcol];
            }
        }
        if (kv0 > qw0 + 31) return;      // wave fully masked (barriers balanced)

        // ---- S^T = K Q^T  (rows=kv, cols=q=lo), log2-scaled
        f32x4 s[2][4] = {};
        __builtin_amdgcn_s_setprio(1);
#pragma unroll
        for (int ks = 0; ks < 2; ++ks) {
            bf16x8 kf[4];
#pragma unroll
            for (int nj = 0; nj < 4; ++nj)
                kf[nj] = *(const bf16x8*)((char*)Ks + (nj * 16 + lo) * 128 +
                                          ((((ks << 2) + hi) ^ sw) << 4));
#pragma unroll
            for (int mi = 0; mi < 2; ++mi)
#pragma unroll
                for (int nj = 0; nj < 4; ++nj)
                    s[mi][nj] = __builtin_amdgcn_mfma_f32_16x16x32_bf16(
                        kf[nj], qf[mi][ks], s[mi][nj], 0, 0, 0);
        }
        __builtin_amdgcn_s_setprio(0);

        // ---- causal mask
        if (kv0 + 63 > qw0) {
#pragma unroll
            for (int mi = 0; mi < 2; ++mi) {
                const int gq = qw0 + mi * 16 + lo;
#pragma unroll
                for (int nj = 0; nj < 4; ++nj)
#pragma unroll
                    for (int r = 0; r < 4; ++r) {
                        const int gk = kv0 + nj * 16 + hi * 4 + r;
                        if (gk > gq) s[mi][nj][r] = -1e30f;
                    }
            }
        }

        // ---- online softmax (q=lo lane-local), defer-max THR=8 (log2)
        float tl[2], corr[2];
#pragma unroll
        for (int mi = 0; mi < 2; ++mi) {
            float m = s[mi][0][0];
#pragma unroll
            for (int nj = 0; nj < 4; ++nj)
#pragma unroll
                for (int r = 0; r < 4; ++r) m = fmaxf(m, s[mi][nj][r]);
            tl[mi] = m;
        }
        const bool grow = (tl[0] > mrow[0] + 8.f) | (tl[1] > mrow[1] + 8.f);
        if (__any(grow)) {
#pragma unroll
            for (int mi = 0; mi < 2; ++mi) {
                float m2 = fmaxf(tl[mi], __shfl_xor(tl[mi], 16));
                m2 = fmaxf(m2, __shfl_xor(m2, 32));
                const float mn = fmaxf(mrow[mi], m2);
                corr[mi] = exp2_fast(mrow[mi] - mn);
                mrow[mi] = mn;
            }
#pragma unroll
            for (int mi = 0; mi < 2; ++mi)
#pragma unroll
                for (int r = 0; r < 4; ++r) {
                    const float cb = __shfl(corr[mi], hi * 4 + r);
#pragma unroll
                    for (int ni = 0; ni < 4; ++ni) o[mi][ni][r] *= cb;
                }
        } else { corr[0] = 1.f; corr[1] = 1.f; }

#pragma unroll
        for (int mi = 0; mi < 2; ++mi) {
            float ls = 0.f;
#pragma unroll
            for (int nj = 0; nj < 4; ++nj) {
#pragma unroll
                for (int r = 0; r < 4; ++r) {
                    const float p = exp2_fast(s[mi][nj][r] - mrow[mi]);
                    s[mi][nj][r] = p;
                    ls += p;
                }
                uint2 pp;
                pp.x = cvt_pk_bf16(s[mi][nj][0], s[mi][nj][1]);
                pp.y = cvt_pk_bf16(s[mi][nj][2], s[mi][nj][3]);
                const int gP = ((nj << 1) + (hi >> 1)) ^ sw;
                *(uint2*)(PqW + (mi * 16 + lo) * 128 + (gP << 4) + ((hi & 1) << 3)) = pp;
            }
            ls += __shfl_xor(ls, 16);
            ls += __shfl_xor(ls, 32);
            lrow[mi] = lrow[mi] * corr[mi] + ls;
        }

        // ---- O += P V
        __builtin_amdgcn_s_setprio(1);
#pragma unroll
        for (int ks2 = 0; ks2 < 2; ++ks2) {
            bf16x8 pf[2], vf[4];
#pragma unroll
            for (int mi = 0; mi < 2; ++mi)
                pf[mi] = *(const bf16x8*)(PqW + (mi * 16 + lo) * 128 +
                                          ((((ks2 << 2) + hi) ^ sw) << 4));
#pragma unroll
            for (int ni = 0; ni < 4; ++ni)
                vf[ni] = *(const bf16x8*)((char*)Vs + (ni * 16 + lo) * 128 +
                                          ((((ks2 << 2) + hi) ^ sw) << 4));
#pragma unroll
            for (int mi = 0; mi < 2; ++mi)
#pragma unroll
                for (int ni = 0; ni < 4; ++ni)
                    o[mi][ni] = __builtin_amdgcn_mfma_f32_16x16x32_bf16(
                        pf[mi], vf[ni], o[mi][ni], 0, 0, 0);
        }
        __builtin_amdgcn_s_setprio(0);
    };

    for (int tt = 0; tt < ntiles; tt += 2) {
        tile_body(tt,     kregA, vregA);   // even tile: buffer A
        tile_body(tt + 1, kregB, vregB);   // odd tile:  buffer B
    }

    // ---- epilogue
#pragma unroll
    for (int mi = 0; mi < 2; ++mi) {
        const float rv = 1.0f / lrow[mi];
#pragma unroll
        for (int r = 0; r < 4; ++r) {
            const float rb = __shfl(rv, hi * 4 + r);
            const int gq = qw0 + mi * 16 + hi * 4 + r;
#pragma unroll
            for (int ni = 0; ni < 4; ++ni)
                ctx[((size_t)(b * SEQ + gq)) * D_MODEL + h * DHEAD + ni * 16 + lo] =
                    f2bf(o[mi][ni][r] * rb);
        }
    }
}

// ---------------------------------------------------------------- launch
extern "C" void kernel_launch(void* const* d_in, const int* in_sizes, int n_in,
                              void* d_out, int out_size, void* d_ws, size_t ws_size,
                              hipStream_t stream) {
    const float* x  = (const float*)d_in[0];
    const float* Wq = (const float*)d_in[1];
    const float* bq = (const float*)d_in[2];
    const float* Wk = (const float*)d_in[3];
    const float* bk = (const float*)d_in[4];
    const float* Wv = (const float*)d_in[5];
    const float* bv = (const float*)d_in[6];
    const float* Wo = (const float*)d_in[7];
    const float* bo = (const float*)d_in[8];

    char* ws = (char*)d_ws;
    ushort* xb  = (ushort*)(ws);
    ushort* wb  = (ushort*)(ws + (16u << 20));
    ushort* Qb  = (ushort*)(ws + (24u << 20));
    ushort* Kb  = (ushort*)(ws + (40u << 20));
    ushort* Vtb = (ushort*)(ws + (56u << 20));
    ushort* ctx = (ushort*)(ws + (72u << 20));

    convert_kernel<<<2048, 256, 0, stream>>>(
        (const float4*)x, (const float4*)Wq, (const float4*)Wk,
        (const float4*)Wv, (const float4*)Wo, (ushort4*)xb, (ushort4*)wb);

    const int NW = D_MODEL * D_MODEL;
    const float qscale = 0.125f * 1.44269504f;   // fold log2e: softmax in exp2 domain

    gemm_qkv<<<384, 512, 0, stream>>>(xb, wb, bq, bk, bv, Qb, Kb, Vtb, qscale);

    attn_kernel<<<1024, 256, 0, stream>>>(Qb, Kb, Vtb, ctx);

    gemm_out<<<128, 512, 0, stream>>>(ctx, wb + 3 * NW, bo, (float*)d_out);
}